// Round 1
// baseline (357.350 us; speedup 1.0000x reference)
//
// LinOSS layer (B=16, N=4096, q=256) on MI355X gfx950.
// Round 7: GEMMs rebuilt on the known-good async-staging structure.
//   prep:   u -> bf16 (ws), W_B/W_C/W_D -> bf16 (ws)           [new]
//   gemm1b: ub @ WBb^T -> fx = dt*s*Bu (fp32) into y-region of d_out
//           (128x128 tile, BK=32, double-buffered global_load_lds(16B),
//            2-phase pipeline, XOR-swizzled LDS, XCD-paired blocks)
//   scan:   3-phase chunked linear recurrence, fp32, in place; scan3 also
//           writes y as bf16 into ws for gemm2b
//   gemm2b: yb @ WCb^T + ub @ WDb^T -> erf-GELU -> g*sigmoid(g) + u -> out0
// Old fp32-staging kernels retained as fallback when ws_size < ~68.6 MB.

#include <hip/hip_runtime.h>
#include <hip/hip_bf16.h>
#include <cstdint>

typedef __bf16 bf16_t;
typedef __bf16 bf16x8 __attribute__((ext_vector_type(8)));
typedef float f32x4 __attribute__((ext_vector_type(4)));

#define B_SZ 16
#define N_SZ 4096
#define Q_SZ 256
#define M_TOT (B_SZ * N_SZ) /* 65536 */
#define DT (1.0f / 4096.0f)
#define LDST 40 /* old-path LDS row stride in bf16 elems */
#define CHUNKS 16
#define CLEN (N_SZ / CHUNKS) /* 256 */
#define PF 8

// ---------------- shared helpers ----------------

// load 8 contiguous fp32, convert to bf16x8 (RNE)
__device__ __forceinline__ bf16x8 load8f(const float* p) {
  const float4 v0 = *(const float4*)p;
  const float4 v1 = *(const float4*)(p + 4);
  bf16x8 v;
  v[0] = (bf16_t)v0.x; v[1] = (bf16_t)v0.y; v[2] = (bf16_t)v0.z; v[3] = (bf16_t)v0.w;
  v[4] = (bf16_t)v1.x; v[5] = (bf16_t)v1.y; v[6] = (bf16_t)v1.z; v[7] = (bf16_t)v1.w;
  return v;
}

// async 16B global->LDS (dest is wave-uniform base + lane*16; we pass the
// per-lane ptr whose readfirstlane IS that base)
__device__ __forceinline__ void gll16(const bf16_t* g, bf16_t* l) {
  __builtin_amdgcn_global_load_lds(
      (const __attribute__((address_space(1))) void*)g,
      (__attribute__((address_space(3))) void*)l, 16, 0, 0);
}

// ---------------- new bf16 GEMM path ----------------
// Tile geometry: BM=BN=128, BK=32 (64B rows, 4x 16B chunks per row).
// LDS tile layout: linear [row][chunk], data chunk swizzled by
// chunk_pos = chunk_data ^ ((row>>1)&3)  -> b128 frag reads are 2-way (free).
// Staging: per K-step 8 KB per matrix = 2 rounds x 256 threads x 16B, with the
// swizzle applied to the GLOBAL source address (LDS dest stays linear).

__device__ __forceinline__ void stage2(const bf16_t* __restrict__ A,
                                       const bf16_t* __restrict__ Bm,
                                       int m0, int n0, int k0, int t,
                                       bf16_t* As, bf16_t* Bs) {
#pragma unroll
  for (int j = 0; j < 2; ++j) {
    const int i = j * 256 + t;       // 16B-chunk index, 0..511
    const int row = i >> 2;          // 0..127
    const int cpos = i & 3;          // chunk slot in LDS
    const int cdat = cpos ^ ((row >> 1) & 3); // data chunk to fetch
    bf16_t* la = As + (size_t)i * 8;
    bf16_t* lb = Bs + (size_t)i * 8;
    gll16(A + (size_t)(m0 + row) * Q_SZ + k0 + cdat * 8, la);
    gll16(Bm + (size_t)(n0 + row) * Q_SZ + k0 + cdat * 8, lb);
  }
}

__device__ __forceinline__ void mstep(const bf16_t* As, const bf16_t* Bs,
                                      int t, f32x4 acc[4][4]) {
  const int lane = t & 63, ln = lane & 15, quad = lane >> 4;
  const int wave = t >> 6;
  const int wm = (wave & 1) * 64, wn = (wave >> 1) * 64;
  const int csw = (quad ^ ((ln >> 1) & 3)) * 8; // swizzled 16B chunk, elem offset
  bf16x8 af[4], bv[4];
#pragma unroll
  for (int mi = 0; mi < 4; ++mi) {
    af[mi] = *(const bf16x8*)(As + (wm + mi * 16 + ln) * 32 + csw);
    bv[mi] = *(const bf16x8*)(Bs + (wn + mi * 16 + ln) * 32 + csw);
  }
#pragma unroll
  for (int mi = 0; mi < 4; ++mi)
#pragma unroll
    for (int ni = 0; ni < 4; ++ni)
      acc[mi][ni] = __builtin_amdgcn_mfma_f32_16x16x32_bf16(af[mi], bv[ni],
                                                            acc[mi][ni], 0, 0, 0);
}

// prep: u (65536x256 fp32) -> ub bf16; WB/WC/WD (256x256 fp32) -> bf16
__global__ __launch_bounds__(256) void prep_kernel(
    const float* __restrict__ u, const float* __restrict__ WB,
    const float* __restrict__ WC, const float* __restrict__ WD,
    bf16_t* __restrict__ ub, bf16_t* __restrict__ WBb,
    bf16_t* __restrict__ WCb, bf16_t* __restrict__ WDb) {
  const int g = blockIdx.x * 256 + threadIdx.x;
  const int UC = (M_TOT * Q_SZ) / 8; // 2,097,152 chunks of 8
  const float* src;
  bf16_t* dst;
  int idx;
  if (g < UC) {
    src = u; dst = ub; idx = g;
  } else {
    const int h = g - UC;            // 0..24575
    const int w = h >> 13;           // 8192 chunks per weight
    idx = h & 8191;
    src = (w == 0) ? WB : (w == 1) ? WC : WD;
    dst = (w == 0) ? WBb : (w == 1) ? WCb : WDb;
  }
  *(bf16x8*)(dst + (size_t)idx * 8) = load8f(src + (size_t)idx * 8);
}

// gemm1b: fx[m,p] = dt*s_p*(sum_q ub[m,q] WBb[p,q] + bB[p])
__global__ __launch_bounds__(256) void gemm1b_kernel(
    const bf16_t* __restrict__ ub, const bf16_t* __restrict__ WBb,
    const float* __restrict__ a, const float* __restrict__ bB,
    float* __restrict__ fx) {
  __shared__ __align__(16) bf16_t As[2][128 * 32];
  __shared__ __align__(16) bf16_t Bs[2][128 * 32];
  const int t = threadIdx.x;
  const int bid = blockIdx.x;
  const int swz = (bid & 7) * 128 + (bid >> 3); // bijective XCD swizzle, nwg=1024
  const int m0 = (swz >> 1) * 128, n0 = (swz & 1) * 128;
  f32x4 acc[4][4] = {};
  stage2(ub, WBb, m0, n0, 0, t, As[0], Bs[0]);
  __syncthreads();
#pragma unroll 2
  for (int k = 0; k < 8; ++k) {
    const int cur = k & 1;
    if (k < 7)
      stage2(ub, WBb, m0, n0, (k + 1) * 32, t, As[cur ^ 1], Bs[cur ^ 1]);
    mstep(As[cur], Bs[cur], t, acc);
    __syncthreads();
  }
  const int lane = t & 63, ln = lane & 15, quad = lane >> 4;
  const int wave = t >> 6;
  const int wm = (wave & 1) * 64, wn = (wave >> 1) * 64;
#pragma unroll
  for (int ni = 0; ni < 4; ++ni) {
    const int gp = n0 + wn + ni * 16 + ln;
    const float av = a[gp];
    const float s = 1.0f / (1.0f + DT * DT * av);
    const float sc = DT * s;
    const float bb = bB[gp];
#pragma unroll
    for (int mi = 0; mi < 4; ++mi) {
      const int gm = m0 + wm + mi * 16 + quad * 4;
#pragma unroll
      for (int r2 = 0; r2 < 4; ++r2)
        fx[(size_t)(gm + r2) * Q_SZ + gp] = sc * (acc[mi][ni][r2] + bb);
    }
  }
}

// gemm2b: x = yb@WCb^T + ub@WDb^T + bC + bD; g = gelu_erf(x); out0 = g*sig(g)+u
__global__ __launch_bounds__(256) void gemm2b_kernel(
    const bf16_t* __restrict__ yb, const bf16_t* __restrict__ WCb,
    const bf16_t* __restrict__ ub, const bf16_t* __restrict__ WDb,
    const float* __restrict__ u, const float* __restrict__ bC,
    const float* __restrict__ bD, float* __restrict__ out0) {
  __shared__ __align__(16) bf16_t As[2][128 * 32];
  __shared__ __align__(16) bf16_t Bs[2][128 * 32];
  const int t = threadIdx.x;
  const int bid = blockIdx.x;
  const int swz = (bid & 7) * 128 + (bid >> 3);
  const int m0 = (swz >> 1) * 128, n0 = (swz & 1) * 128;
  f32x4 acc[4][4] = {};
  stage2(yb, WCb, m0, n0, 0, t, As[0], Bs[0]);
  __syncthreads();
#pragma unroll 2
  for (int kk = 0; kk < 16; ++kk) { // virtual K=512: [0..7]=yb/WCb, [8..15]=ub/WDb
    const int cur = kk & 1;
    if (kk < 15) {
      const int nk = kk + 1;
      const bf16_t* Ap = (nk < 8) ? yb : ub;
      const bf16_t* Bp = (nk < 8) ? WCb : WDb;
      stage2(Ap, Bp, m0, n0, (nk & 7) * 32, t, As[cur ^ 1], Bs[cur ^ 1]);
    }
    mstep(As[cur], Bs[cur], t, acc);
    __syncthreads();
  }
  const int lane = t & 63, ln = lane & 15, quad = lane >> 4;
  const int wave = t >> 6;
  const int wm = (wave & 1) * 64, wn = (wave >> 1) * 64;
#pragma unroll
  for (int ni = 0; ni < 4; ++ni) {
    const int gp = n0 + wn + ni * 16 + ln;
    const float bias = bC[gp] + bD[gp];
#pragma unroll
    for (int mi = 0; mi < 4; ++mi) {
      const int gm = m0 + wm + mi * 16 + quad * 4;
#pragma unroll
      for (int r2 = 0; r2 < 4; ++r2) {
        const float x = acc[mi][ni][r2] + bias;
        const float g = 0.5f * x * (1.0f + erff(x * 0.70710678118654752f));
        const float sg = 1.0f / (1.0f + __expf(-g));
        const float uu = u[(size_t)(gm + r2) * Q_SZ + gp];
        out0[(size_t)(gm + r2) * Q_SZ + gp] = fmaf(g, sg, uu);
      }
    }
  }
}

// ---------------- scan (3-phase chunked) ----------------

__global__ __launch_bounds__(256) void scan1_kernel(
    const float* __restrict__ fx, const float* __restrict__ a,
    float* __restrict__ ex, float* __restrict__ ez) {
  const int g = blockIdx.x * 256 + threadIdx.x;
  const int p = g & 255, c = (g >> 8) & (CHUNKS - 1), b = g >> 12;
  const float av = a[p];
  const float s = 1.0f / (1.0f + DT * DT * av);
  const float dsa = DT * s * av, dss = DT * s;
  float x = 0.f, z = 0.f;
  const float* fp = fx + ((size_t)b * N_SZ + c * CLEN) * Q_SZ + p;
  float buf[PF], nbuf[PF];
#pragma unroll
  for (int j = 0; j < PF; ++j) buf[j] = fp[(size_t)j * Q_SZ];
  for (int n = 0; n < CLEN; n += PF) {
    if (n + PF < CLEN) {
#pragma unroll
      for (int j = 0; j < PF; ++j) nbuf[j] = fp[(size_t)(n + PF + j) * Q_SZ];
    }
#pragma unroll
    for (int j = 0; j < PF; ++j) {
      const float f = buf[j];
      const float xn = fmaf(s, x, fmaf(-dsa, z, f));
      const float zn = fmaf(dss, x, fmaf(s, z, DT * f));
      x = xn; z = zn;
    }
#pragma unroll
    for (int j = 0; j < PF; ++j) buf[j] = nbuf[j];
  }
  ex[g] = x; ez[g] = z;
}

__global__ __launch_bounds__(256) void scan2_kernel(
    const float* __restrict__ a, const float* __restrict__ ex,
    const float* __restrict__ ez, float* __restrict__ ix, float* __restrict__ iz) {
  const int g = blockIdx.x * 256 + threadIdx.x;
  const int p = g & 255, b = g >> 8;
  const float av = a[p];
  const float s = 1.0f / (1.0f + DT * DT * av);
  float m00 = s, m01 = -DT * s * av, m10 = DT * s, m11 = s;
#pragma unroll
  for (int i = 0; i < 8; ++i) {
    const float a00 = fmaf(m00, m00, m01 * m10);
    const float a01 = m01 * (m00 + m11);
    const float a10 = m10 * (m00 + m11);
    const float a11 = fmaf(m11, m11, m01 * m10);
    m00 = a00; m01 = a01; m10 = a10; m11 = a11;
  }
  float x = 0.f, z = 0.f;
  for (int c = 0; c < CHUNKS; ++c) {
    const size_t idx = ((size_t)b * CHUNKS + c) * Q_SZ + p;
    ix[idx] = x; iz[idx] = z;
    const float xn = fmaf(m00, x, fmaf(m01, z, ex[idx]));
    const float zn = fmaf(m10, x, fmaf(m11, z, ez[idx]));
    x = xn; z = zn;
  }
}

// phase 3: rescan from true initial states; y overwrites fx; optional bf16 copy
__global__ __launch_bounds__(256) void scan3_kernel(
    const float* __restrict__ a, const float* __restrict__ ix,
    const float* __restrict__ iz, float* __restrict__ yf,
    bf16_t* __restrict__ yb) {
  const int g = blockIdx.x * 256 + threadIdx.x;
  const int p = g & 255, c = (g >> 8) & (CHUNKS - 1), b = g >> 12;
  const float av = a[p];
  const float s = 1.0f / (1.0f + DT * DT * av);
  const float dsa = DT * s * av, dss = DT * s;
  float x = ix[g], z = iz[g];
  const size_t base = ((size_t)b * N_SZ + c * CLEN) * Q_SZ + p;
  float* yp = yf + base;
  bf16_t* ybp = yb ? yb + base : nullptr;
  float buf[PF], nbuf[PF];
#pragma unroll
  for (int j = 0; j < PF; ++j) buf[j] = yp[(size_t)j * Q_SZ];
  for (int n = 0; n < CLEN; n += PF) {
    if (n + PF < CLEN) {
#pragma unroll
      for (int j = 0; j < PF; ++j) nbuf[j] = yp[(size_t)(n + PF + j) * Q_SZ];
    }
#pragma unroll
    for (int j = 0; j < PF; ++j) {
      const float f = buf[j];
      const float xn = fmaf(s, x, fmaf(-dsa, z, f));
      const float zn = fmaf(dss, x, fmaf(s, z, DT * f));
      x = xn; z = zn;
      yp[(size_t)(n + j) * Q_SZ] = zn;
      if (yb) ybp[(size_t)(n + j) * Q_SZ] = (bf16_t)zn;
    }
#pragma unroll
    for (int j = 0; j < PF; ++j) buf[j] = nbuf[j];
  }
}

__global__ __launch_bounds__(256) void scan_mono_kernel(
    const float* __restrict__ a, float* __restrict__ yf) {
  const int g = blockIdx.x * 256 + threadIdx.x;
  const int p = g & 255, b = g >> 8;
  const float av = a[p];
  const float s = 1.0f / (1.0f + DT * DT * av);
  const float dsa = DT * s * av, dss = DT * s;
  float x = 0.f, z = 0.f;
  float* yp = yf + (size_t)b * N_SZ * Q_SZ + p;
  float buf[PF], nbuf[PF];
#pragma unroll
  for (int j = 0; j < PF; ++j) buf[j] = yp[(size_t)j * Q_SZ];
  for (int n = 0; n < N_SZ; n += PF) {
    if (n + PF < N_SZ) {
#pragma unroll
      for (int j = 0; j < PF; ++j) nbuf[j] = yp[(size_t)(n + PF + j) * Q_SZ];
    }
#pragma unroll
    for (int j = 0; j < PF; ++j) {
      const float f = buf[j];
      const float xn = fmaf(s, x, fmaf(-dsa, z, f));
      const float zn = fmaf(dss, x, fmaf(s, z, DT * f));
      x = xn; z = zn;
      yp[(size_t)(n + j) * Q_SZ] = zn;
    }
#pragma unroll
    for (int j = 0; j < PF; ++j) buf[j] = nbuf[j];
  }
}

// ---------------- old fp32-staging GEMM path (fallback) ----------------

__device__ __forceinline__ void kloop(const float* __restrict__ Ap,
                                      const float* __restrict__ Bp,
                                      int m0, int n0, int t,
                                      bf16_t* As, bf16_t* Bs, f32x4 acc[4][4]) {
  const int r = t >> 2, cc = t & 3;
  const int lane = t & 63, ln = lane & 15, quad = lane >> 4;
  const int wave = t >> 6;
  const int wm = (wave & 1) * 64, wn = (wave >> 1) * 64;

  for (int k0 = 0; k0 < Q_SZ; k0 += 32) {
#pragma unroll
    for (int i = 0; i < 2; ++i) {
      const int row = r + i * 64;
      const int col = k0 + cc * 8;
      *(bf16x8*)(As + row * LDST + cc * 8) =
          load8f(Ap + (size_t)(m0 + row) * Q_SZ + col);
      *(bf16x8*)(Bs + row * LDST + cc * 8) =
          load8f(Bp + (size_t)(n0 + row) * Q_SZ + col);
    }
    __syncthreads();
    bf16x8 af[4], bv[4];
#pragma unroll
    for (int mi = 0; mi < 4; ++mi) {
      af[mi] = *(const bf16x8*)(As + (wm + mi * 16 + ln) * LDST + quad * 8);
      bv[mi] = *(const bf16x8*)(Bs + (wn + mi * 16 + ln) * LDST + quad * 8);
    }
#pragma unroll
    for (int mi = 0; mi < 4; ++mi)
#pragma unroll
      for (int ni = 0; ni < 4; ++ni)
        acc[mi][ni] = __builtin_amdgcn_mfma_f32_16x16x32_bf16(af[mi], bv[ni],
                                                              acc[mi][ni], 0, 0, 0);
    __syncthreads();
  }
}

__global__ __launch_bounds__(256) void gemm1_kernel(
    const float* __restrict__ u, const float* __restrict__ WB,
    const float* __restrict__ a, const float* __restrict__ bB,
    float* __restrict__ fx) {
  __shared__ __align__(16) bf16_t As[128 * LDST];
  __shared__ __align__(16) bf16_t Bs[128 * LDST];
  const int t = threadIdx.x;
  const int m0 = blockIdx.x * 128, n0 = blockIdx.y * 128;
  f32x4 acc[4][4] = {};
  kloop(u, WB, m0, n0, t, As, Bs, acc);

  const int lane = t & 63, ln = lane & 15, quad = lane >> 4;
  const int wave = t >> 6;
  const int wm = (wave & 1) * 64, wn = (wave >> 1) * 64;
#pragma unroll
  for (int ni = 0; ni < 4; ++ni) {
    const int gp = n0 + wn + ni * 16 + ln;
    const float av = a[gp];
    const float s = 1.0f / (1.0f + DT * DT * av);
    const float sc = DT * s;
    const float bb = bB[gp];
#pragma unroll
    for (int mi = 0; mi < 4; ++mi) {
      const int gm = m0 + wm + mi * 16 + quad * 4;
#pragma unroll
      for (int r2 = 0; r2 < 4; ++r2)
        fx[(size_t)(gm + r2) * Q_SZ + gp] = sc * (acc[mi][ni][r2] + bb);
    }
  }
}

__global__ __launch_bounds__(256) void gemm2_kernel(
    const float* __restrict__ y, const float* __restrict__ WC,
    const float* __restrict__ u, const float* __restrict__ WD,
    const float* __restrict__ bC, const float* __restrict__ bD,
    float* __restrict__ out0) {
  __shared__ __align__(16) bf16_t As[128 * LDST];
  __shared__ __align__(16) bf16_t Bs[128 * LDST];
  const int t = threadIdx.x;
  const int m0 = blockIdx.x * 128, n0 = blockIdx.y * 128;
  f32x4 acc[4][4] = {};
  kloop(y, WC, m0, n0, t, As, Bs, acc);
  kloop(u, WD, m0, n0, t, As, Bs, acc);

  const int lane = t & 63, ln = lane & 15, quad = lane >> 4;
  const int wave = t >> 6;
  const int wm = (wave & 1) * 64, wn = (wave >> 1) * 64;
#pragma unroll
  for (int ni = 0; ni < 4; ++ni) {
    const int gp = n0 + wn + ni * 16 + ln;
    const float bias = bC[gp] + bD[gp];
#pragma unroll
    for (int mi = 0; mi < 4; ++mi) {
      const int gm = m0 + wm + mi * 16 + quad * 4;
#pragma unroll
      for (int r2 = 0; r2 < 4; ++r2) {
        const float x = acc[mi][ni][r2] + bias;
        const float g = 0.5f * x * (1.0f + erff(x * 0.70710678118654752f));
        const float sg = 1.0f / (1.0f + __expf(-g));
        const float uu = u[(size_t)(gm + r2) * Q_SZ + gp];
        out0[(size_t)(gm + r2) * Q_SZ + gp] = fmaf(g, sg, uu);
      }
    }
  }
}

// ---------------- launcher ----------------

extern "C" void kernel_launch(void* const* d_in, const int* in_sizes, int n_in,
                              void* d_out, int out_size, void* d_ws, size_t ws_size,
                              hipStream_t stream) {
  const float* u  = (const float*)d_in[0];
  const float* a  = (const float*)d_in[1];
  const float* WB = (const float*)d_in[2];
  const float* bB = (const float*)d_in[3];
  const float* WC = (const float*)d_in[4];
  const float* bC = (const float*)d_in[5];
  const float* WD = (const float*)d_in[6];
  const float* bD = (const float*)d_in[7];

  float* out0 = (float*)d_out;                // first 16.7M fp32: out
  float* yreg = out0 + (size_t)M_TOT * Q_SZ;  // second 16.7M fp32: fx -> y

  const size_t UB_ELEMS = (size_t)M_TOT * Q_SZ;          // 16,777,216
  const size_t W_ELEMS = (size_t)Q_SZ * Q_SZ;            // 65,536
  const size_t state_bytes = 4 * (size_t)M_TOT * sizeof(float); // 1 MiB
  const size_t need_full =
      (2 * UB_ELEMS + 3 * W_ELEMS) * sizeof(bf16_t) + state_bytes; // ~68.6 MB

  if (ws_size >= need_full) {
    bf16_t* ub  = (bf16_t*)d_ws;
    bf16_t* yb  = ub + UB_ELEMS;
    bf16_t* WBb = yb + UB_ELEMS;
    bf16_t* WCb = WBb + W_ELEMS;
    bf16_t* WDb = WCb + W_ELEMS;
    float* ex = (float*)(WDb + W_ELEMS);
    float* ez = ex + M_TOT;
    float* ix = ez + M_TOT;
    float* iz = ix + M_TOT;

    prep_kernel<<<8288, 256, 0, stream>>>(u, WB, WC, WD, ub, WBb, WCb, WDb);
    gemm1b_kernel<<<1024, 256, 0, stream>>>(ub, WBb, a, bB, yreg);
    scan1_kernel<<<256, 256, 0, stream>>>(yreg, a, ex, ez);
    scan2_kernel<<<16, 256, 0, stream>>>(a, ex, ez, ix, iz);
    scan3_kernel<<<256, 256, 0, stream>>>(a, ix, iz, yreg, yb);
    gemm2b_kernel<<<1024, 256, 0, stream>>>(yb, WCb, ub, WDb, u, bC, bD, out0);
  } else {
    dim3 gg(M_TOT / 128, Q_SZ / 128);
    gemm1_kernel<<<gg, 256, 0, stream>>>(u, WB, a, bB, yreg);
    if (ws_size >= state_bytes) {
      float* ex = (float*)d_ws;
      float* ez = ex + M_TOT;
      float* ix = ez + M_TOT;
      float* iz = ix + M_TOT;
      scan1_kernel<<<256, 256, 0, stream>>>(yreg, a, ex, ez);
      scan2_kernel<<<16, 256, 0, stream>>>(a, ex, ez, ix, iz);
      scan3_kernel<<<256, 256, 0, stream>>>(a, ix, iz, yreg, (bf16_t*)nullptr);
    } else {
      scan_mono_kernel<<<16, 256, 0, stream>>>(a, yreg);
    }
    gemm2_kernel<<<gg, 256, 0, stream>>>(yreg, WC, u, WD, bC, bD, out0);
  }
}